// Round 4
// baseline (239.711 us; speedup 1.0000x reference)
//
#include <hip/hip_runtime.h>
#include <hip/hip_bf16.h>

#define B_  16
#define LQ  2048
#define LS  2048
#define DD  512
#define BQ  128
#define BS  256
#define BK  64
#define NSB (LS / BS)   // 8 s-blocks total
#define NKC (DD / BK)   // 8 k-stages per s-block
#define NSPLIT 2

typedef short bf16x8 __attribute__((ext_vector_type(8)));
typedef float f32x4  __attribute__((ext_vector_type(4)));

// async global->LDS, 16B per lane. LDS dest = wave-uniform base + lane*16.
__device__ __forceinline__ void load_lds16(const void* g, void* l) {
  __builtin_amdgcn_global_load_lds((const __attribute__((address_space(1))) void*)g,
                                   (__attribute__((address_space(3))) void*)l,
                                   16, 0, 0);
}

__device__ __forceinline__ unsigned short f2bf(float f) {
  union { float f; unsigned int u; } v; v.f = f;
  unsigned int r = v.u + 0x7fffu + ((v.u >> 16) & 1u);  // RNE
  return (unsigned short)(r >> 16);
}

// Exact-size grid: blocks [0, nblk) convert Q, [nblk, 2nblk) convert S.
__global__ __launch_bounds__(256) void cvt_kernel(const float* __restrict__ Q,
                                                  const float* __restrict__ S,
                                                  unsigned short* __restrict__ Qw,
                                                  unsigned short* __restrict__ Sw,
                                                  int nblk) {
  int blk = blockIdx.x;
  const float* src; unsigned short* dst;
  if (blk < nblk) { src = Q; dst = Qw; } else { src = S; dst = Sw; blk -= nblk; }
  int i = blk * 256 + threadIdx.x;   // float4 index
  float4 f = ((const float4*)src)[i];
  ushort4 u;
  u.x = f2bf(f.x); u.y = f2bf(f.y); u.z = f2bf(f.z); u.w = f2bf(f.w);
  ((ushort4*)dst)[i] = u;
}

// score[b,q] = sum_s softmax(l)[s]*l[s],  l[s] = Q[b,q,:].S[b,s,:]
// MFMA: A = S-tile (M=s), B = Q-tile^T (N=q) -> C[row=s][col=q]
// C layout (16x16x32): col = lane&15, row = (lane>>4)*4 + reg  [m89/m91]
//
// Round-4 structure: 1024 threads = 16 waves (4/SIMD from ONE block — don't
// bet on multi-block residency), 256s x 128q tile, LDS double-buffered with a
// SINGLE barrier per BK=64 stage: stage t+1's global_load_lds are issued into
// buf^1 before computing stage t, so the staging latency overlaps a full
// compute stage (and the per-s-block exp epilogue overlaps the next loads).
// LDS k-chunk XOR swizzle (round 2): conflict-free fragment reads.
__global__ __launch_bounds__(1024, 4) void attn_kernel(const unsigned short* __restrict__ Qw,
                                                       const unsigned short* __restrict__ Sw,
                                                       float* __restrict__ out,
                                                       float* __restrict__ pm,
                                                       float* __restrict__ pse,
                                                       float* __restrict__ psel,
                                                       int nsplit) {
  __shared__ __align__(16) unsigned short sQ[2][BQ * BK];  // 2 x 16 KiB
  __shared__ __align__(16) unsigned short sS[2][BS * BK];  // 2 x 32 KiB

  const int qb   = blockIdx.x;
  const int b    = blockIdx.y;
  const int spl  = blockIdx.z;
  const int tid  = threadIdx.x;
  const int w    = tid >> 6;      // 0..15
  const int lane = tid & 63;
  const int h    = w & 3;         // s-quarter: rows [h*64, h*64+64)
  const int g    = w >> 2;        // q-group: cols [g*32, g*32+32)
  const int col  = lane & 15;
  const int quad = lane >> 4;
  const int c7   = col & 7;

  const int q0 = qb * BQ;
  const unsigned short* Qb = Qw + (size_t)b * LQ * DD;
  const unsigned short* Sb = Sw + (size_t)b * LS * DD;

  float mst[2] = { -INFINITY, -INFINITY };
  float se[2]  = { 0.f, 0.f };
  float sel[2] = { 0.f, 0.f };

  f32x4 acc[4][2];   // [s-tile within quarter][q-tile] = 32 VGPRs

  const int rr = lane >> 3;                 // row within 8-row staging unit
  const int cc = ((lane & 7) ^ rr) * 8;     // swizzled global k-chunk (elements)

  const int sbp = NSB / nsplit;             // s-blocks per split
  const int sbs = spl * sbp;
  const int T   = sbp * NKC;                // total BK-stages

  // stage t: sb = sbs + (t>>3), kc = t&7. Each wave issues 3 load_lds16:
  //   sQ rows [w*8, w*8+8), sS rows [w*8,..) and [128+w*8,..)
  auto issue = [&](int t, int buf) {
    const int sb = sbs + (t >> 3);
    const int kc = t & 7;
    const int s0 = sb * BS;
    const int kb = kc * BK + cc;
    load_lds16(Qb + (size_t)(q0 + w * 8 + rr) * DD + kb,        &sQ[buf][(w * 8) * BK]);
    load_lds16(Sb + (size_t)(s0 + w * 8 + rr) * DD + kb,        &sS[buf][(w * 8) * BK]);
    load_lds16(Sb + (size_t)(s0 + 128 + w * 8 + rr) * DD + kb,  &sS[buf][(128 + w * 8) * BK]);
  };

  issue(0, 0);

  for (int t = 0; t < T; ++t) {
    const int buf = t & 1;
    __syncthreads();              // drains this wave's stage-t loads (issued one stage ago)
    if (t + 1 < T) issue(t + 1, buf ^ 1);

    if ((t & 7) == 0) {
#pragma unroll
      for (int st = 0; st < 4; ++st)
#pragma unroll
        for (int qt = 0; qt < 2; ++qt)
          acc[st][qt] = (f32x4){0.f, 0.f, 0.f, 0.f};
    }

#pragma unroll
    for (int kk = 0; kk < 2; ++kk) {
      const int koff = ((kk * 4 + quad) ^ c7) * 8;
      bf16x8 aq[2], asv[4];
#pragma unroll
      for (int qt = 0; qt < 2; ++qt)
        aq[qt] = *(const bf16x8*)&sQ[buf][(g * 32 + qt * 16 + col) * BK + koff];
#pragma unroll
      for (int st = 0; st < 4; ++st)
        asv[st] = *(const bf16x8*)&sS[buf][(h * 64 + st * 16 + col) * BK + koff];
#pragma unroll
      for (int st = 0; st < 4; ++st)
#pragma unroll
        for (int qt = 0; qt < 2; ++qt)
          acc[st][qt] = __builtin_amdgcn_mfma_f32_16x16x32_bf16(asv[st], aq[qt], acc[st][qt], 0, 0, 0);
    }

    if ((t & 7) == 7) {
      // online softmax-weighted-mean over this wave's 64-s quarter.
      // Runs while the next stage's global_load_lds are in flight.
#pragma unroll
      for (int qt = 0; qt < 2; ++qt) {
        float lmax = mst[qt];
#pragma unroll
        for (int st = 0; st < 4; ++st)
#pragma unroll
          for (int r = 0; r < 4; ++r)
            lmax = fmaxf(lmax, acc[st][qt][r]);
        lmax = fmaxf(lmax, __shfl_xor(lmax, 16, 64));
        lmax = fmaxf(lmax, __shfl_xor(lmax, 32, 64));
        float alpha = __expf(mst[qt] - lmax);  // exp(-inf)=0 on first block
        float pe = 0.f, pel = 0.f;
#pragma unroll
        for (int st = 0; st < 4; ++st)
#pragma unroll
          for (int r = 0; r < 4; ++r) {
            float l = acc[st][qt][r];
            float e = __expf(l - lmax);
            pe += e;
            pel = fmaf(e, l, pel);
          }
        pe  += __shfl_xor(pe, 16, 64);  pe  += __shfl_xor(pe, 32, 64);
        pel += __shfl_xor(pel, 16, 64); pel += __shfl_xor(pel, 32, 64);
        se[qt]  = fmaf(se[qt],  alpha, pe);
        sel[qt] = fmaf(sel[qt], alpha, pel);
        mst[qt] = lmax;
      }
    }
  }

  // merge the 4 s-quarters per q-group via LDS, then write
  __syncthreads();
  float* red = (float*)&sQ[0][0];   // 3 x 512 floats = 6 KiB
  if (quad == 0) {
#pragma unroll
    for (int qt = 0; qt < 2; ++qt) {
      int idx = ((g * 4 + h) * 2 + qt) * 16 + col;
      red[idx]        = mst[qt];
      red[512 + idx]  = se[qt];
      red[1024 + idx] = sel[qt];
    }
  }
  __syncthreads();
  if (h == 0 && quad == 0) {
#pragma unroll
    for (int qt = 0; qt < 2; ++qt) {
      float M = -INFINITY;
#pragma unroll
      for (int hh = 0; hh < 4; ++hh)
        M = fmaxf(M, red[((g * 4 + hh) * 2 + qt) * 16 + col]);
      float SE = 0.f, SEL = 0.f;
#pragma unroll
      for (int hh = 0; hh < 4; ++hh) {
        int idx = ((g * 4 + hh) * 2 + qt) * 16 + col;
        float a = __expf(red[idx] - M);
        SE  = fmaf(red[512 + idx],  a, SE);
        SEL = fmaf(red[1024 + idx], a, SEL);
      }
      size_t qi = (size_t)b * LQ + q0 + g * 32 + qt * 16 + col;
      if (nsplit == 1) {
        out[qi] = SEL / SE;
      } else {
        pm[qi * NSPLIT + spl]   = M;
        pse[qi * NSPLIT + spl]  = SE;
        psel[qi * NSPLIT + spl] = SEL;
      }
    }
  }
}

__global__ __launch_bounds__(256) void combine_kernel(const float* __restrict__ pm,
                                                      const float* __restrict__ pse,
                                                      const float* __restrict__ psel,
                                                      float* __restrict__ out) {
  int i = blockIdx.x * blockDim.x + threadIdx.x;
  if (i >= B_ * LQ) return;
  float M = -INFINITY;
#pragma unroll
  for (int s = 0; s < NSPLIT; ++s) M = fmaxf(M, pm[i * NSPLIT + s]);
  float SE = 0.f, SEL = 0.f;
#pragma unroll
  for (int s = 0; s < NSPLIT; ++s) {
    float a = __expf(pm[i * NSPLIT + s] - M);
    SE  = fmaf(pse[i * NSPLIT + s],  a, SE);
    SEL = fmaf(psel[i * NSPLIT + s], a, SEL);
  }
  out[i] = SEL / SE;
}

// fp32 fallback (correctness insurance if ws too small)
__global__ __launch_bounds__(256) void fallback_kernel(const float* __restrict__ Q,
                                                       const float* __restrict__ S,
                                                       float* __restrict__ out) {
  __shared__ float qv[DD];
  __shared__ float red[256];
  const int b = blockIdx.y, qi = blockIdx.x, tid = threadIdx.x;
  const float* qrow = Q + ((size_t)b * LQ + qi) * DD;
  for (int d = tid; d < DD; d += 256) qv[d] = qrow[d];
  __syncthreads();
  const float* Sb = S + (size_t)b * LS * DD;
  float m = -INFINITY, se = 0.f, sel = 0.f;
  for (int s = tid; s < LS; s += 256) {
    const float* srow = Sb + (size_t)s * DD;
    float dot = 0.f;
    for (int d = 0; d < DD; ++d) dot = fmaf(qv[d], srow[d], dot);
    float mn = fmaxf(m, dot);
    float a = __expf(m - mn);
    float e = __expf(dot - mn);
    se  = se * a + e;
    sel = sel * a + e * dot;
    m = mn;
  }
  red[tid] = m; __syncthreads();
  for (int o = 128; o > 0; o >>= 1) { if (tid < o) red[tid] = fmaxf(red[tid], red[tid + o]); __syncthreads(); }
  float M = red[0]; __syncthreads();
  float a = __expf(m - M); se *= a; sel *= a;
  red[tid] = se; __syncthreads();
  for (int o = 128; o > 0; o >>= 1) { if (tid < o) red[tid] += red[tid + o]; __syncthreads(); }
  float SE = red[0]; __syncthreads();
  red[tid] = sel; __syncthreads();
  for (int o = 128; o > 0; o >>= 1) { if (tid < o) red[tid] += red[tid + o]; __syncthreads(); }
  float SEL = red[0];
  if (tid == 0) out[(size_t)b * LQ + qi] = SEL / SE;
}

extern "C" void kernel_launch(void* const* d_in, const int* in_sizes, int n_in,
                              void* d_out, int out_size, void* d_ws, size_t ws_size,
                              hipStream_t stream) {
  const float* Q = (const float*)d_in[0];
  const float* S = (const float*)d_in[1];
  float* out = (float*)d_out;
  const size_t nelem = (size_t)B_ * LQ * DD;                    // 16.78M / tensor
  const size_t need_base  = 2 * nelem * sizeof(unsigned short); // 67 MiB
  const size_t part_elems = (size_t)B_ * LQ * NSPLIT;
  const size_t need_split = need_base + 3 * part_elems * sizeof(float);

  if (ws_size >= need_base) {
    unsigned short* Qw = (unsigned short*)d_ws;
    unsigned short* Sw = Qw + nelem;
    int nblk = (int)(nelem / 4 / 256);   // exact: nelem divisible by 1024
    cvt_kernel<<<2 * nblk, 256, 0, stream>>>(Q, S, Qw, Sw, nblk);
    if (ws_size >= need_split) {
      float* pm   = (float*)(Sw + nelem);
      float* pse  = pm + part_elems;
      float* psel = pse + part_elems;
      attn_kernel<<<dim3(LQ / BQ, B_, NSPLIT), 1024, 0, stream>>>(Qw, Sw, out, pm, pse, psel, NSPLIT);
      combine_kernel<<<(B_ * LQ + 255) / 256, 256, 0, stream>>>(pm, pse, psel, out);
    } else {
      attn_kernel<<<dim3(LQ / BQ, B_, 1), 1024, 0, stream>>>(Qw, Sw, out, nullptr, nullptr, nullptr, 1);
    }
  } else {
    fallback_kernel<<<dim3(LQ, B_), 256, 0, stream>>>(Q, S, out);
  }
}

// Round 5
// 238.010 us; speedup vs baseline: 1.0071x; 1.0071x over previous
//
#include <hip/hip_runtime.h>
#include <hip/hip_bf16.h>

#define B_  16
#define LQ  2048
#define LS  2048
#define DD  512
#define BQ  256
#define BS  256
#define BK  64
#define NSB (LS / BS)   // 8 s-blocks total
#define NKC (DD / BK)   // 8 k-stages per s-block
#define NSPLIT 2

typedef short bf16x8 __attribute__((ext_vector_type(8)));
typedef float f32x4  __attribute__((ext_vector_type(4)));

// async global->LDS, 16B per lane. LDS dest = wave-uniform base + lane*16.
__device__ __forceinline__ void load_lds16(const void* g, void* l) {
  __builtin_amdgcn_global_load_lds((const __attribute__((address_space(1))) void*)g,
                                   (__attribute__((address_space(3))) void*)l,
                                   16, 0, 0);
}

__device__ __forceinline__ unsigned short f2bf(float f) {
  union { float f; unsigned int u; } v; v.f = f;
  unsigned int r = v.u + 0x7fffu + ((v.u >> 16) & 1u);  // RNE
  return (unsigned short)(r >> 16);
}

// Exact-size grid: blocks [0, nblk) convert Q, [nblk, 2nblk) convert S.
__global__ __launch_bounds__(256) void cvt_kernel(const float* __restrict__ Q,
                                                  const float* __restrict__ S,
                                                  unsigned short* __restrict__ Qw,
                                                  unsigned short* __restrict__ Sw,
                                                  int nblk) {
  int blk = blockIdx.x;
  const float* src; unsigned short* dst;
  if (blk < nblk) { src = Q; dst = Qw; } else { src = S; dst = Sw; blk -= nblk; }
  int i = blk * 256 + threadIdx.x;   // float4 index
  float4 f = ((const float4*)src)[i];
  ushort4 u;
  u.x = f2bf(f.x); u.y = f2bf(f.y); u.z = f2bf(f.z); u.w = f2bf(f.w);
  ((ushort4*)dst)[i] = u;
}

// score[b,q] = sum_s softmax(l)[s]*l[s],  l[s] = Q[b,q,:].S[b,s,:]
// MFMA: A = S-tile (M=s), B = Q-tile^T (N=q) -> C[row=s][col=q]
// C layout (16x16x32): col = lane&15, row = (lane>>4)*4 + reg  [m89/m91]
//
// Round-5: 1024 thr = 16 waves, block tile 256s x 256q, wave tile 64s x 64q
// (st=4,qt=4 -> 0.5 ds_read_b128 per MFMA, the r3/r4 LDS wall halved).
// Double-buffered LDS (128 KB), ONE barrier per BK=64 stage; stage t+1 issued
// before computing stage t. Stage compute (~3k cyc) now covers the staged
// bytes' arrival, unlike r4 where thin stages exposed the DMA latency.
// XCD swizzle: id = qb*32 + (b*2+spl) -> the 8 qb-blocks sharing one S-half
// live at the same id%8 (= same XCD); 4 S-halves/XCD = 4 MB = its L2, so S
// re-reads hit L2 instead of HBM (r4's 262 MB fetch vs 64 MB unique).
// LDS k-chunk XOR swizzle (r2): conflict-free fragment reads.
__global__ __launch_bounds__(1024, 4) void attn_kernel(const unsigned short* __restrict__ Qw,
                                                       const unsigned short* __restrict__ Sw,
                                                       float* __restrict__ pm,
                                                       float* __restrict__ pse,
                                                       float* __restrict__ psel) {
  __shared__ __align__(16) unsigned short sQ[2][BQ * BK];  // 2 x 32 KiB
  __shared__ __align__(16) unsigned short sS[2][BS * BK];  // 2 x 32 KiB

  const int id   = blockIdx.x;
  const int qb   = id >> 5;       // 0..7
  const int bs   = id & 31;
  const int b    = bs >> 1;       // 0..15
  const int spl  = bs & 1;        // 0..1
  const int tid  = threadIdx.x;
  const int w    = tid >> 6;      // 0..15
  const int lane = tid & 63;
  const int h    = w & 3;         // s-quarter: rows [h*64, h*64+64)
  const int g    = w >> 2;        // q-quarter: cols [g*64, g*64+64)
  const int col  = lane & 15;
  const int quad = lane >> 4;
  const int c7   = col & 7;

  const int q0 = qb * BQ;
  const unsigned short* Qb = Qw + (size_t)b * LQ * DD;
  const unsigned short* Sb = Sw + (size_t)b * LS * DD;

  float mst[4] = { -INFINITY, -INFINITY, -INFINITY, -INFINITY };
  float se[4]  = { 0.f, 0.f, 0.f, 0.f };
  float sel[4] = { 0.f, 0.f, 0.f, 0.f };

  f32x4 acc[4][4];   // [s-tile][q-tile] = 64 VGPRs

  const int rr = lane >> 3;                 // row within 8-row staging unit
  const int cc = ((lane & 7) ^ rr) * 8;     // swizzled global k-chunk (elements)

  const int sbp = NSB / NSPLIT;             // 4 s-blocks per split
  const int sbs = spl * sbp;
  const int T   = sbp * NKC;                // 32 BK-stages

  // stage t: sb = sbs + (t>>3), kc = t&7. Waves 0-7 stage sQ rows [w*32,+32),
  // waves 8-15 stage sS rows [(w-8)*32,+32); 4 issues x 8 rows each.
  auto issue = [&](int t, int buf) {
    const int kb = (t & 7) * BK + cc;
    if (w < 8) {
      const int r0 = w * 32;
#pragma unroll
      for (int i = 0; i < 4; ++i)
        load_lds16(Qb + (size_t)(q0 + r0 + i * 8 + rr) * DD + kb, &sQ[buf][(r0 + i * 8) * BK]);
    } else {
      const int s0 = (sbs + (t >> 3)) * BS + (w - 8) * 32;
      const int l0 = (w - 8) * 32;
#pragma unroll
      for (int i = 0; i < 4; ++i)
        load_lds16(Sb + (size_t)(s0 + i * 8 + rr) * DD + kb, &sS[buf][(l0 + i * 8) * BK]);
    }
  };

  issue(0, 0);

  for (int t = 0; t < T; ++t) {
    const int buf = t & 1;
    __syncthreads();              // drains stage t's loads (issued one stage ago)
    if (t + 1 < T) issue(t + 1, buf ^ 1);

    if ((t & 7) == 0) {
#pragma unroll
      for (int st = 0; st < 4; ++st)
#pragma unroll
        for (int qt = 0; qt < 4; ++qt)
          acc[st][qt] = (f32x4){0.f, 0.f, 0.f, 0.f};
    }

#pragma unroll
    for (int kk = 0; kk < 2; ++kk) {
      const int koff = ((kk * 4 + quad) ^ c7) * 8;
      bf16x8 aq[4], asv[4];
#pragma unroll
      for (int qt = 0; qt < 4; ++qt)
        aq[qt] = *(const bf16x8*)&sQ[buf][(g * 64 + qt * 16 + col) * BK + koff];
#pragma unroll
      for (int st = 0; st < 4; ++st)
        asv[st] = *(const bf16x8*)&sS[buf][(h * 64 + st * 16 + col) * BK + koff];
#pragma unroll
      for (int st = 0; st < 4; ++st)
#pragma unroll
        for (int qt = 0; qt < 4; ++qt)
          acc[st][qt] = __builtin_amdgcn_mfma_f32_16x16x32_bf16(asv[st], aq[qt], acc[st][qt], 0, 0, 0);
    }

    if ((t & 7) == 7) {
      // online softmax-weighted-mean over this wave's 64-s quarter;
      // runs while the next stage's global_load_lds are in flight.
#pragma unroll
      for (int qt = 0; qt < 4; ++qt) {
        float lmax = mst[qt];
#pragma unroll
        for (int st = 0; st < 4; ++st)
#pragma unroll
          for (int r = 0; r < 4; ++r)
            lmax = fmaxf(lmax, acc[st][qt][r]);
        lmax = fmaxf(lmax, __shfl_xor(lmax, 16, 64));
        lmax = fmaxf(lmax, __shfl_xor(lmax, 32, 64));
        float alpha = __expf(mst[qt] - lmax);  // exp(-inf)=0 on first block
        float pe = 0.f, pel = 0.f;
#pragma unroll
        for (int st = 0; st < 4; ++st)
#pragma unroll
          for (int r = 0; r < 4; ++r) {
            float l = acc[st][qt][r];
            float e = __expf(l - lmax);
            pe += e;
            pel = fmaf(e, l, pel);
          }
        pe  += __shfl_xor(pe, 16, 64);  pe  += __shfl_xor(pe, 32, 64);
        pel += __shfl_xor(pel, 16, 64); pel += __shfl_xor(pel, 32, 64);
        se[qt]  = fmaf(se[qt],  alpha, pe);
        sel[qt] = fmaf(sel[qt], alpha, pel);
        mst[qt] = lmax;
      }
    }
  }

  // merge the 4 s-quarters per q-col via LDS, write split partials
  __syncthreads();
  float* red = (float*)&sQ[0][0];   // 3 x 1024 floats = 12 KiB
  if (quad == 0) {
#pragma unroll
    for (int qt = 0; qt < 4; ++qt) {
      int idx = ((g * 4 + h) * 4 + qt) * 16 + col;
      red[idx]        = mst[qt];
      red[1024 + idx] = se[qt];
      red[2048 + idx] = sel[qt];
    }
  }
  __syncthreads();
  if (h == 0 && quad == 0) {
#pragma unroll
    for (int qt = 0; qt < 4; ++qt) {
      float M = -INFINITY;
#pragma unroll
      for (int hh = 0; hh < 4; ++hh)
        M = fmaxf(M, red[((g * 4 + hh) * 4 + qt) * 16 + col]);
      float SE = 0.f, SEL = 0.f;
#pragma unroll
      for (int hh = 0; hh < 4; ++hh) {
        int idx = ((g * 4 + hh) * 4 + qt) * 16 + col;
        float a = __expf(red[idx] - M);
        SE  = fmaf(red[1024 + idx], a, SE);
        SEL = fmaf(red[2048 + idx], a, SEL);
      }
      size_t qi = (size_t)b * LQ + q0 + g * 64 + qt * 16 + col;
      pm[qi * NSPLIT + spl]   = M;
      pse[qi * NSPLIT + spl]  = SE;
      psel[qi * NSPLIT + spl] = SEL;
    }
  }
}

__global__ __launch_bounds__(256) void combine_kernel(const float* __restrict__ pm,
                                                      const float* __restrict__ pse,
                                                      const float* __restrict__ psel,
                                                      float* __restrict__ out) {
  int i = blockIdx.x * blockDim.x + threadIdx.x;
  if (i >= B_ * LQ) return;
  float M = -INFINITY;
#pragma unroll
  for (int s = 0; s < NSPLIT; ++s) M = fmaxf(M, pm[i * NSPLIT + s]);
  float SE = 0.f, SEL = 0.f;
#pragma unroll
  for (int s = 0; s < NSPLIT; ++s) {
    float a = __expf(pm[i * NSPLIT + s] - M);
    SE  = fmaf(pse[i * NSPLIT + s],  a, SE);
    SEL = fmaf(psel[i * NSPLIT + s], a, SEL);
  }
  out[i] = SEL / SE;
}

// fp32 fallback (correctness insurance if ws too small)
__global__ __launch_bounds__(256) void fallback_kernel(const float* __restrict__ Q,
                                                       const float* __restrict__ S,
                                                       float* __restrict__ out) {
  __shared__ float qv[DD];
  __shared__ float red[256];
  const int b = blockIdx.y, qi = blockIdx.x, tid = threadIdx.x;
  const float* qrow = Q + ((size_t)b * LQ + qi) * DD;
  for (int d = tid; d < DD; d += 256) qv[d] = qrow[d];
  __syncthreads();
  const float* Sb = S + (size_t)b * LS * DD;
  float m = -INFINITY, se = 0.f, sel = 0.f;
  for (int s = tid; s < LS; s += 256) {
    const float* srow = Sb + (size_t)s * DD;
    float dot = 0.f;
    for (int d = 0; d < DD; ++d) dot = fmaf(qv[d], srow[d], dot);
    float mn = fmaxf(m, dot);
    float a = __expf(m - mn);
    float e = __expf(dot - mn);
    se  = se * a + e;
    sel = sel * a + e * dot;
    m = mn;
  }
  red[tid] = m; __syncthreads();
  for (int o = 128; o > 0; o >>= 1) { if (tid < o) red[tid] = fmaxf(red[tid], red[tid + o]); __syncthreads(); }
  float M = red[0]; __syncthreads();
  float a = __expf(m - M); se *= a; sel *= a;
  red[tid] = se; __syncthreads();
  for (int o = 128; o > 0; o >>= 1) { if (tid < o) red[tid] += red[tid + o]; __syncthreads(); }
  float SE = red[0]; __syncthreads();
  red[tid] = sel; __syncthreads();
  for (int o = 128; o > 0; o >>= 1) { if (tid < o) red[tid] += red[tid + o]; __syncthreads(); }
  float SEL = red[0];
  if (tid == 0) out[(size_t)b * LQ + qi] = SEL / SE;
}

extern "C" void kernel_launch(void* const* d_in, const int* in_sizes, int n_in,
                              void* d_out, int out_size, void* d_ws, size_t ws_size,
                              hipStream_t stream) {
  const float* Q = (const float*)d_in[0];
  const float* S = (const float*)d_in[1];
  float* out = (float*)d_out;
  const size_t nelem = (size_t)B_ * LQ * DD;                    // 16.78M / tensor
  const size_t part_elems = (size_t)B_ * LQ * NSPLIT;
  const size_t need = 2 * nelem * sizeof(unsigned short)        // 67 MiB
                    + 3 * part_elems * sizeof(float);           // + 1.5 MiB

  if (ws_size >= need) {
    unsigned short* Qw = (unsigned short*)d_ws;
    unsigned short* Sw = Qw + nelem;
    float* pm   = (float*)(Sw + nelem);
    float* pse  = pm + part_elems;
    float* psel = pse + part_elems;
    int nblk = (int)(nelem / 4 / 256);   // exact: nelem divisible by 1024
    cvt_kernel<<<2 * nblk, 256, 0, stream>>>(Q, S, Qw, Sw, nblk);
    attn_kernel<<<(LQ / BQ) * B_ * NSPLIT, 1024, 0, stream>>>(Qw, Sw, pm, pse, psel);
    combine_kernel<<<(B_ * LQ + 255) / 256, 256, 0, stream>>>(pm, pse, psel, out);
  } else {
    fallback_kernel<<<dim3(LQ, B_), 256, 0, stream>>>(Q, S, out);
  }
}

// Round 6
// 232.583 us; speedup vs baseline: 1.0306x; 1.0233x over previous
//
#include <hip/hip_runtime.h>
#include <hip/hip_bf16.h>

#define B_  16
#define LQ  2048
#define LS  2048
#define DD  512
#define BQ  256
#define BS  256
#define BK  32
#define NSB (LS / BS)    // 8 s-blocks total
#define NKC (DD / BK)    // 16 k-stages per s-block
#define NSPLIT 2
#define T_STAGES ((NSB / NSPLIT) * NKC)   // 64

typedef short bf16x8 __attribute__((ext_vector_type(8)));
typedef float f32x4  __attribute__((ext_vector_type(4)));
typedef unsigned short u16x8 __attribute__((ext_vector_type(8)));

// async global->LDS, 16B per lane. LDS dest = wave-uniform base + lane*16.
__device__ __forceinline__ void load_lds16(const void* g, void* l) {
  __builtin_amdgcn_global_load_lds((const __attribute__((address_space(1))) void*)g,
                                   (__attribute__((address_space(3))) void*)l,
                                   16, 0, 0);
}

__device__ __forceinline__ unsigned short f2bf(float f) {
  union { float f; unsigned int u; } v; v.f = f;
  unsigned int r = v.u + 0x7fffu + ((v.u >> 16) & 1u);  // RNE
  return (unsigned short)(r >> 16);
}

// 8 elems/thread: 2 float4 reads -> one 16B store.
__global__ __launch_bounds__(256) void cvt_kernel(const float* __restrict__ Q,
                                                  const float* __restrict__ S,
                                                  unsigned short* __restrict__ Qw,
                                                  unsigned short* __restrict__ Sw,
                                                  int nblk) {
  int blk = blockIdx.x;
  const float* src; unsigned short* dst;
  if (blk < nblk) { src = Q; dst = Qw; } else { src = S; dst = Sw; blk -= nblk; }
  int i = blk * 256 + threadIdx.x;   // 8-elem index
  float4 f0 = ((const float4*)src)[i * 2];
  float4 f1 = ((const float4*)src)[i * 2 + 1];
  u16x8 u;
  u[0] = f2bf(f0.x); u[1] = f2bf(f0.y); u[2] = f2bf(f0.z); u[3] = f2bf(f0.w);
  u[4] = f2bf(f1.x); u[5] = f2bf(f1.y); u[6] = f2bf(f1.z); u[7] = f2bf(f1.w);
  ((u16x8*)dst)[i] = u;
}

// score[b,q] = sum_s softmax(l)[s]*l[s],  l[s] = Q[b,q,:].S[b,s,:]
// MFMA: A = S-tile (M=s), B = Q-tile^T (N=q) -> C[row=s][col=q]
// C layout (16x16x32): col = lane&15, row = (lane>>4)*4 + reg  [m89/m91]
//
// Round-6: kill the per-stage vmcnt(0) drain (r5: 7.6k cyc/stage vs 1.5k
// compute). BK=32 stages (32 KB), FOUR statically-named LDS buffers in an
// unrolled x4 ring, depth-3 prefetch (96 KB in flight), raw s_barrier via asm
// + manual s_waitcnt vmcnt(4): each wave has exactly 2 DMA loads/stage, so at
// the wait point stages t..t+2 are outstanding (6) and vmcnt(4) retires
// exactly stage t. Static buffer names let the waitcnt pass disambiguate
// ds_read vs in-flight DMA to other buffers. Ghost-clamped tail issues keep
// the count uniform. Swizzle for BK=32 (row=64B): chunk c stored at
// c^(r&3)^((r>>2)&3) -> b128 fragment reads uniform 8/bank (conflict-free).
__global__ __launch_bounds__(1024, 4) void attn_kernel(const unsigned short* __restrict__ Qw,
                                                       const unsigned short* __restrict__ Sw,
                                                       float* __restrict__ pm,
                                                       float* __restrict__ pse,
                                                       float* __restrict__ psel) {
  __shared__ __align__(16) unsigned short sQ0[BQ * BK], sS0[BS * BK];  // 16+16 KiB
  __shared__ __align__(16) unsigned short sQ1[BQ * BK], sS1[BS * BK];
  __shared__ __align__(16) unsigned short sQ2[BQ * BK], sS2[BS * BK];
  __shared__ __align__(16) unsigned short sQ3[BQ * BK], sS3[BS * BK];  // 128 KiB total

  const int id   = blockIdx.x;
  const int qb   = id >> 5;       // 0..7
  const int bsx  = id & 31;
  const int b    = bsx >> 1;      // 0..15  (XCD swizzle: id%8 groups share S-half)
  const int spl  = bsx & 1;
  const int tid  = threadIdx.x;
  const int w    = tid >> 6;      // 0..15
  const int lane = tid & 63;
  const int h    = w & 3;         // s-quarter: rows [h*64, +64)
  const int g    = w >> 2;        // q-quarter: cols [g*64, +64)
  const int col  = lane & 15;
  const int quad = lane >> 4;

  const int q0 = qb * BQ;
  const unsigned short* Qb = Qw + (size_t)b * LQ * DD;
  const unsigned short* Sb = Sw + (size_t)b * LS * DD;

  float mst[4] = { -INFINITY, -INFINITY, -INFINITY, -INFINITY };
  float se[4]  = { 0.f, 0.f, 0.f, 0.f };
  float sel[4] = { 0.f, 0.f, 0.f, 0.f };
  f32x4 acc[4][4];

  // staging: wave w stages rows [16w, 16w+16) of each tile; lane i covers
  // row 16w+(i>>2), stored chunk position i&3, which holds global chunk
  // (i&3)^((i>>2)&3)^((i>>4)&3)  (r&3 = (i>>2)&3, (r>>2)&3 = (i>>4)&3 here).
  const int qrow   = 16 * w + (lane >> 2);
  const int cchunk = (lane & 3) ^ ((lane >> 2) & 3) ^ ((lane >> 4) & 3);
  const int ldsoff = w * 512;     // elements; 1 KB unit per wave

  const int sbs = spl * (NSB / NSPLIT);

  auto issue = [&](int t, unsigned short* bq, unsigned short* bss) {
    const int ts = t < T_STAGES ? t : T_STAGES - 1;   // ghost-clamp (uniform vmcnt)
    const int kb = (ts & 15) * BK + cchunk * 8;
    const int s0 = (sbs + (ts >> 4)) * BS;
    load_lds16(Qb + (size_t)(q0 + qrow) * DD + kb, bq + ldsoff);
    load_lds16(Sb + (size_t)(s0 + qrow) * DD + kb, bss + ldsoff);
  };

  // fragment read position: row = base+col (base mult of 16) ->
  // pos = quad ^ (col&3) ^ ((col>>2)&3)
  const int pos = (quad ^ (col & 3) ^ ((col >> 2) & 3)) * 8;

  auto compute = [&](const unsigned short* bq, const unsigned short* bss) {
    bf16x8 aq[4], asv[4];
#pragma unroll
    for (int qt = 0; qt < 4; ++qt)
      aq[qt] = *(const bf16x8*)&bq[(g * 64 + qt * 16 + col) * BK + pos];
#pragma unroll
    for (int st = 0; st < 4; ++st)
      asv[st] = *(const bf16x8*)&bss[(h * 64 + st * 16 + col) * BK + pos];
#pragma unroll
    for (int st = 0; st < 4; ++st)
#pragma unroll
      for (int qt = 0; qt < 4; ++qt)
        acc[st][qt] = __builtin_amdgcn_mfma_f32_16x16x32_bf16(asv[st], aq[qt], acc[st][qt], 0, 0, 0);
  };

  auto initacc = [&]() {
#pragma unroll
    for (int st = 0; st < 4; ++st)
#pragma unroll
      for (int qt = 0; qt < 4; ++qt)
        acc[st][qt] = (f32x4){0.f, 0.f, 0.f, 0.f};
  };

  auto epilogue = [&]() {
    // online softmax-weighted-mean over this wave's 64-s quarter; runs while
    // the next stages' DMA is in flight.
#pragma unroll
    for (int qt = 0; qt < 4; ++qt) {
      float lmax = mst[qt];
#pragma unroll
      for (int st = 0; st < 4; ++st)
#pragma unroll
        for (int r = 0; r < 4; ++r)
          lmax = fmaxf(lmax, acc[st][qt][r]);
      lmax = fmaxf(lmax, __shfl_xor(lmax, 16, 64));
      lmax = fmaxf(lmax, __shfl_xor(lmax, 32, 64));
      float alpha = __expf(mst[qt] - lmax);
      float pe = 0.f, pel = 0.f;
#pragma unroll
      for (int st = 0; st < 4; ++st)
#pragma unroll
        for (int r = 0; r < 4; ++r) {
          float l = acc[st][qt][r];
          float e = __expf(l - lmax);
          pe += e;
          pel = fmaf(e, l, pel);
        }
      pe  += __shfl_xor(pe, 16, 64);  pe  += __shfl_xor(pe, 32, 64);
      pel += __shfl_xor(pel, 16, 64); pel += __shfl_xor(pel, 32, 64);
      se[qt]  = fmaf(se[qt],  alpha, pe);
      sel[qt] = fmaf(sel[qt], alpha, pel);
      mst[qt] = lmax;
    }
  };

#define STEP(t, RQ, RS, WQ, WS)                                   \
  do {                                                            \
    asm volatile("s_waitcnt vmcnt(4)" ::: "memory");              \
    asm volatile("s_barrier" ::: "memory");                       \
    issue((t) + 3, WQ, WS);                                       \
    if (((t) & 15) == 0) initacc();                               \
    compute(RQ, RS);                                              \
    if (((t) & 15) == 15) epilogue();                             \
  } while (0)

  issue(0, sQ0, sS0);
  issue(1, sQ1, sS1);
  issue(2, sQ2, sS2);

  for (int tt = 0; tt < T_STAGES; tt += 4) {
    STEP(tt + 0, sQ0, sS0, sQ3, sS3);
    STEP(tt + 1, sQ1, sS1, sQ0, sS0);
    STEP(tt + 2, sQ2, sS2, sQ1, sS1);
    STEP(tt + 3, sQ3, sS3, sQ2, sS2);
  }
#undef STEP

  // merge the 4 s-quarters per q-col via LDS, write split partials
  __syncthreads();   // drains ghost DMA too
  float* red = (float*)&sQ0[0];   // 12 KiB
  if (quad == 0) {
#pragma unroll
    for (int qt = 0; qt < 4; ++qt) {
      int idx = ((g * 4 + h) * 4 + qt) * 16 + col;
      red[idx]        = mst[qt];
      red[1024 + idx] = se[qt];
      red[2048 + idx] = sel[qt];
    }
  }
  __syncthreads();
  if (h == 0 && quad == 0) {
#pragma unroll
    for (int qt = 0; qt < 4; ++qt) {
      float M = -INFINITY;
#pragma unroll
      for (int hh = 0; hh < 4; ++hh)
        M = fmaxf(M, red[((g * 4 + hh) * 4 + qt) * 16 + col]);
      float SE = 0.f, SEL = 0.f;
#pragma unroll
      for (int hh = 0; hh < 4; ++hh) {
        int idx = ((g * 4 + hh) * 4 + qt) * 16 + col;
        float a = __expf(red[idx] - M);
        SE  = fmaf(red[1024 + idx], a, SE);
        SEL = fmaf(red[2048 + idx], a, SEL);
      }
      size_t qi = (size_t)b * LQ + q0 + g * 64 + qt * 16 + col;
      pm[qi * NSPLIT + spl]   = M;
      pse[qi * NSPLIT + spl]  = SE;
      psel[qi * NSPLIT + spl] = SEL;
    }
  }
}

__global__ __launch_bounds__(256) void combine_kernel(const float* __restrict__ pm,
                                                      const float* __restrict__ pse,
                                                      const float* __restrict__ psel,
                                                      float* __restrict__ out) {
  int i = blockIdx.x * blockDim.x + threadIdx.x;
  if (i >= B_ * LQ) return;
  float M = -INFINITY;
#pragma unroll
  for (int s = 0; s < NSPLIT; ++s) M = fmaxf(M, pm[i * NSPLIT + s]);
  float SE = 0.f, SEL = 0.f;
#pragma unroll
  for (int s = 0; s < NSPLIT; ++s) {
    float a = __expf(pm[i * NSPLIT + s] - M);
    SE  = fmaf(pse[i * NSPLIT + s],  a, SE);
    SEL = fmaf(psel[i * NSPLIT + s], a, SEL);
  }
  out[i] = SEL / SE;
}

// fp32 fallback (correctness insurance if ws too small)
__global__ __launch_bounds__(256) void fallback_kernel(const float* __restrict__ Q,
                                                       const float* __restrict__ S,
                                                       float* __restrict__ out) {
  __shared__ float qv[DD];
  __shared__ float red[256];
  const int b = blockIdx.y, qi = blockIdx.x, tid = threadIdx.x;
  const float* qrow = Q + ((size_t)b * LQ + qi) * DD;
  for (int d = tid; d < DD; d += 256) qv[d] = qrow[d];
  __syncthreads();
  const float* Sb = S + (size_t)b * LS * DD;
  float m = -INFINITY, se = 0.f, sel = 0.f;
  for (int s = tid; s < LS; s += 256) {
    const float* srow = Sb + (size_t)s * DD;
    float dot = 0.f;
    for (int d = 0; d < DD; ++d) dot = fmaf(qv[d], srow[d], dot);
    float mn = fmaxf(m, dot);
    float a = __expf(m - mn);
    float e = __expf(dot - mn);
    se  = se * a + e;
    sel = sel * a + e * dot;
    m = mn;
  }
  red[tid] = m; __syncthreads();
  for (int o = 128; o > 0; o >>= 1) { if (tid < o) red[tid] = fmaxf(red[tid], red[tid + o]); __syncthreads(); }
  float M = red[0]; __syncthreads();
  float a = __expf(m - M); se *= a; sel *= a;
  red[tid] = se; __syncthreads();
  for (int o = 128; o > 0; o >>= 1) { if (tid < o) red[tid] += red[tid + o]; __syncthreads(); }
  float SE = red[0]; __syncthreads();
  red[tid] = sel; __syncthreads();
  for (int o = 128; o > 0; o >>= 1) { if (tid < o) red[tid] += red[tid + o]; __syncthreads(); }
  float SEL = red[0];
  if (tid == 0) out[(size_t)b * LQ + qi] = SEL / SE;
}

extern "C" void kernel_launch(void* const* d_in, const int* in_sizes, int n_in,
                              void* d_out, int out_size, void* d_ws, size_t ws_size,
                              hipStream_t stream) {
  const float* Q = (const float*)d_in[0];
  const float* S = (const float*)d_in[1];
  float* out = (float*)d_out;
  const size_t nelem = (size_t)B_ * LQ * DD;                    // 16.78M / tensor
  const size_t part_elems = (size_t)B_ * LQ * NSPLIT;
  const size_t need = 2 * nelem * sizeof(unsigned short)        // 67 MiB
                    + 3 * part_elems * sizeof(float);           // + <1 MiB

  if (ws_size >= need) {
    unsigned short* Qw = (unsigned short*)d_ws;
    unsigned short* Sw = Qw + nelem;
    float* pm   = (float*)(Sw + nelem);
    float* pse  = pm + part_elems;
    float* psel = pse + part_elems;
    int nblk = (int)(nelem / 8 / 256);   // exact: nelem divisible by 2048
    cvt_kernel<<<2 * nblk, 256, 0, stream>>>(Q, S, Qw, Sw, nblk);
    attn_kernel<<<(LQ / BQ) * B_ * NSPLIT, 1024, 0, stream>>>(Qw, Sw, pm, pse, psel);
    combine_kernel<<<(B_ * LQ + 255) / 256, 256, 0, stream>>>(pm, pse, psel, out);
  } else {
    fallback_kernel<<<dim3(LQ, B_), 256, 0, stream>>>(Q, S, out);
  }
}